// Round 1
// baseline (190.381 us; speedup 1.0000x reference)
//
#include <hip/hip_runtime.h>

// PlateYoloBlock: (32,13,256,256) fp32 -> (32,65536,13) fp32
// out[b][y*256+x][c]:
//   c=0: (sigmoid(v)+x)*8   c=1: (sigmoid(v)+y)*8
//   c=2,3: exp(v)*8         c=4..11: v*8          c=12: sigmoid(v)
// Pure HBM-streaming transpose; LDS staging gives coalesced loads AND stores.

#define NB      32
#define NC      13
#define HW      65536     // 256*256 positions per batch
#define WIDTH   256
#define TILE    512       // positions per block (divides HW; whole tile in one batch)
#define THREADS 256

__device__ __forceinline__ float sigmoidf_(float x) {
    return 1.0f / (1.0f + __expf(-x));
}

__global__ __launch_bounds__(THREADS) void plate_yolo_kernel(
        const float* __restrict__ in, float* __restrict__ out) {
    __shared__ float lds[TILE * NC];   // 26,624 B -> 6 blocks/CU

    const int tid = threadIdx.x;
    const long long s0 = (long long)blockIdx.x * TILE;   // global spatial index base
    const int b = (int)(s0 >> 16);                       // 65536 positions per batch
    const int posBase = (int)(s0 & (HW - 1));
    const float* __restrict__ inB = in + (long long)b * NC * HW + posBase;

    // Stage 1: coalesced per-channel loads -> pointwise math -> LDS in output layout.
    // LDS write stride across lanes = 13 floats; gcd(13,32)=1 -> 2-way/bank (free).
    #pragma unroll
    for (int k = 0; k < TILE / THREADS; ++k) {
        const int p = tid + k * THREADS;            // local position in tile
        const int pos = posBase + p;                // position within batch
        const float fx = (float)(pos & (WIDTH - 1));
        const float fy = (float)(pos >> 8);
        #pragma unroll
        for (int c = 0; c < NC; ++c) {
            float v = inB[c * HW + p];
            float r;
            if (c == 0)                 r = (sigmoidf_(v) + fx) * 8.0f;
            else if (c == 1)            r = (sigmoidf_(v) + fy) * 8.0f;
            else if (c == 2 || c == 3)  r = __expf(v) * 8.0f;
            else if (c == 12)           r = sigmoidf_(v);
            else                        r = v * 8.0f;
            lds[p * NC + c] = r;
        }
    }
    __syncthreads();

    // Stage 2: contiguous float4 copy-out (ds_read_b128 + global_store_dwordx4).
    // Tile base byte offset = blockIdx.x * 512*13*4 = multiple of 16 -> aligned.
    const float4* __restrict__ src = (const float4*)lds;
    float4* __restrict__ dst = (float4*)(out + s0 * NC);
    const int n4 = TILE * NC / 4;   // 1664
    #pragma unroll
    for (int j = tid; j < n4; j += THREADS) {
        dst[j] = src[j];
    }
}

extern "C" void kernel_launch(void* const* d_in, const int* in_sizes, int n_in,
                              void* d_out, int out_size, void* d_ws, size_t ws_size,
                              hipStream_t stream) {
    const float* in = (const float*)d_in[0];
    float* out = (float*)d_out;
    const int blocks = (NB * HW) / TILE;   // 4096
    plate_yolo_kernel<<<blocks, THREADS, 0, stream>>>(in, out);
}